// Round 6
// baseline (351.418 us; speedup 1.0000x reference)
//
#include <hip/hip_runtime.h>
#include <hip/hip_bf16.h>
#include <cstdint>
#include <cstddef>

// ---------------------------------------------------------------------------
// Cross attention, B=8 N=1024 C=768 HEADS=8 HD=96, sr_ratio=1 path.
//   1. cvt: x,y -> bf16; Wq*SCALE*log2e, Wk, Wv, Wp -> bf16
//   2. fused QKV GEMM (bf16 MFMA 16x16x32, BK=64, XOR swizzle, single-barrier
//      double-buffered staging).  Q,K -> [B][N][C]; V -> [B*H][HD][N]
//   3. flash attention, NO-MAX softmax (bounded scores), 128-q tile,
//      4 waves x 2 strips of 16 q-rows (each LDS B-frag feeds 2 MFMAs),
//      double-buffered K/V staging, rel prefetch 1 tile ahead.
//   4. proj GEMM out = AO@Wp^T + bp -> f32
// ---------------------------------------------------------------------------

using f32x4  = __attribute__((ext_vector_type(4))) float;
using bf16x8 = __attribute__((ext_vector_type(8))) __bf16;

constexpr int Bb = 8, Nn = 1024, Cc = 768;
constexpr float LOG2E = 1.4426950408889634f;
constexpr float QSC   = 0.10206207261596575f * 1.4426950408889634f;  // SCALE*log2e

__device__ __forceinline__ uint16_t f2bf(float f) {
  union { float f; uint32_t u; } v; v.f = f;
  return (uint16_t)((v.u + 0x7fffu + ((v.u >> 16) & 1u)) >> 16);  // RNE
}

__device__ __forceinline__ void gl_lds16(const void* g, void* l) {
  __builtin_amdgcn_global_load_lds(
      (const __attribute__((address_space(1))) void*)g,
      (__attribute__((address_space(3))) void*)l, 16, 0, 0);
}

__device__ __forceinline__ f32x4 mfma16(bf16x8 a, bf16x8 b, f32x4 c) {
  return __builtin_amdgcn_mfma_f32_16x16x32_bf16(a, b, c, 0, 0, 0);
}

// DPP row_ror sum over a 16-lane row (epilogue only)
template <int CTRL>
__device__ __forceinline__ float dpp_add(float v) {
  union { float f; int i; } u, r;
  u.f = v;
  r.i = __builtin_amdgcn_update_dpp(u.i, u.i, CTRL, 0xF, 0xF, false);
  return v + r.f;
}
__device__ __forceinline__ float red16_add(float v) {
  v = dpp_add<0x128>(v);  // row_ror:8
  v = dpp_add<0x124>(v);  // row_ror:4
  v = dpp_add<0x122>(v);  // row_ror:2
  v = dpp_add<0x121>(v);  // row_ror:1
  return v;
}

// ---------------------------------------------------------------------------
__global__ void cvt2_kernel(const float* __restrict__ a,
                            const float* __restrict__ b,
                            uint16_t* __restrict__ da,
                            uint16_t* __restrict__ db, int n4) {
  int i = blockIdx.x * blockDim.x + threadIdx.x;
  const float* s = blockIdx.y ? b : a;
  uint16_t* d = blockIdx.y ? db : da;
  if (i < n4) {
    float4 v = ((const float4*)s)[i];
    ushort4 o;
    o.x = f2bf(v.x); o.y = f2bf(v.y); o.z = f2bf(v.z); o.w = f2bf(v.w);
    ((ushort4*)d)[i] = o;
  }
}

__global__ void cvtw_kernel(const float* __restrict__ wq,
                            const float* __restrict__ wk,
                            const float* __restrict__ wv,
                            const float* __restrict__ wp,
                            uint16_t* __restrict__ dq, uint16_t* __restrict__ dk,
                            uint16_t* __restrict__ dv, uint16_t* __restrict__ dp,
                            int n4) {
  int i = blockIdx.x * blockDim.x + threadIdx.x;
  const float* s; uint16_t* d; float sc = 1.f;
  switch (blockIdx.y) {
    case 0:  s = wq; d = dq; sc = QSC; break;  // fold SCALE*log2e into Wq
    case 1:  s = wk; d = dk; break;
    case 2:  s = wv; d = dv; break;
    default: s = wp; d = dp; break;
  }
  if (i < n4) {
    float4 v = ((const float4*)s)[i];
    ushort4 o;
    o.x = f2bf(v.x * sc); o.y = f2bf(v.y * sc);
    o.z = f2bf(v.z * sc); o.w = f2bf(v.w * sc);
    ((ushort4*)d)[i] = o;
  }
}

// ---------------------------------------------------------------------------
// GEMM core: 128x128 tile, BK=64, XOR-swizzled LDS, single-barrier
// double-buffered staging. M=8192 N=768 K=768, A row-major, Bt = B^T.
__device__ __forceinline__ void gemm_core(const uint16_t* __restrict__ A,
                                          const uint16_t* __restrict__ Bt,
                                          int m0, int n0, f32x4 (&acc)[4][4]) {
  __shared__ uint16_t As[2][128 * 64];
  __shared__ uint16_t Bs[2][128 * 64];
  const int tid = threadIdx.x;
  const int lane = tid & 63, l16 = lane & 15, quad = lane >> 4;
  const int w = tid >> 6;
  const int wm = (w & 1) * 64, wn = (w >> 1) * 64;

  int soff[4];
#pragma unroll
  for (int i = 0; i < 4; ++i) {
    int idx = tid + 256 * i;
    int row = idx >> 3, pc = idx & 7;
    int c = pc ^ (row & 7);           // logical chunk staged at phys pc
    soff[i] = row * 768 + c * 8;
  }

  const uint16_t* Abase = A + (size_t)m0 * 768;
  const uint16_t* Bbase = Bt + (size_t)n0 * 768;
  auto stage = [&](int k0, int buf) {
#pragma unroll
    for (int i = 0; i < 4; ++i)
      gl_lds16(Abase + k0 + soff[i], &As[buf][(tid + 256 * i) * 8]);
#pragma unroll
    for (int i = 0; i < 4; ++i)
      gl_lds16(Bbase + k0 + soff[i], &Bs[buf][(tid + 256 * i) * 8]);
  };

  stage(0, 0);

#pragma unroll 2
  for (int kt = 0; kt < 12; ++kt) {
    const int cur = kt & 1, nxt = (kt + 1) & 1;
    __syncthreads();  // staging of cur drained; prior reads of nxt done
    if (kt < 11) stage((kt + 1) * 64, nxt);

#pragma unroll
    for (int ks = 0; ks < 2; ++ks) {
      bf16x8 a[4], b[4];
      const int phys = (ks * 4 + quad) ^ (l16 & 7);
#pragma unroll
      for (int i = 0; i < 4; ++i)
        a[i] = *(const bf16x8*)&As[cur][(wm + i * 16 + l16) * 64 + phys * 8];
#pragma unroll
      for (int j = 0; j < 4; ++j)
        b[j] = *(const bf16x8*)&Bs[cur][(wn + j * 16 + l16) * 64 + phys * 8];
#pragma unroll
      for (int i = 0; i < 4; ++i)
#pragma unroll
        for (int j = 0; j < 4; ++j)
          acc[i][j] = mfma16(a[i], b[j], acc[i][j]);
    }
  }
}

// Fused Q/K/V projections. Grid (18,64): x/6 -> segment {Q,K,V}.
__global__ __launch_bounds__(256, 2) void qkv_kernel(
    const uint16_t* __restrict__ xb, const uint16_t* __restrict__ yb,
    const uint16_t* __restrict__ wq, const uint16_t* __restrict__ wk,
    const uint16_t* __restrict__ wv, uint16_t* __restrict__ Qb,
    uint16_t* __restrict__ Kb, uint16_t* __restrict__ Vt) {
  const int seg = blockIdx.x / 6, nb = blockIdx.x % 6;
  const uint16_t* A  = (seg == 0) ? xb : yb;
  const uint16_t* Bt = (seg == 0) ? wq : (seg == 1) ? wk : wv;
  const int m0 = blockIdx.y * 128, n0 = nb * 128;

  f32x4 acc[4][4] = {};
  gemm_core(A, Bt, m0, n0, acc);

  const int tid = threadIdx.x, lane = tid & 63;
  const int l16 = lane & 15, quad = lane >> 4, w = tid >> 6;
  const int wm = (w & 1) * 64, wn = (w >> 1) * 64;

  if (seg <= 1) {
    uint16_t* O = seg ? Kb : Qb;
#pragma unroll
    for (int i = 0; i < 4; ++i)
#pragma unroll
      for (int j = 0; j < 4; ++j) {
        int col = n0 + wn + j * 16 + l16;
#pragma unroll
        for (int r = 0; r < 4; ++r) {
          int row = m0 + wm + i * 16 + quad * 4 + r;
          O[(size_t)row * 768 + col] = f2bf(acc[i][j][r]);
        }
      }
  } else {
    // V scatter: Vt[b*8+h][hd][n]
#pragma unroll
    for (int i = 0; i < 4; ++i) {
      int row0 = m0 + wm + i * 16 + quad * 4;
      int bidx = row0 >> 10, nseq = row0 & 1023;
#pragma unroll
      for (int j = 0; j < 4; ++j) {
        int col = n0 + wn + j * 16 + l16;
        int h = col / 96, hd = col % 96;
        ushort4 pk;
        pk.x = f2bf(acc[i][j][0]); pk.y = f2bf(acc[i][j][1]);
        pk.z = f2bf(acc[i][j][2]); pk.w = f2bf(acc[i][j][3]);
        size_t o = (((size_t)(bidx * 8 + h) * 96 + hd) << 10) + nseq;
        *(ushort4*)(Vt + o) = pk;
      }
    }
  }
}

// Output projection: out = AO@Wp^T + bp (f32). Grid (6,64).
__global__ __launch_bounds__(256, 2) void proj_kernel(
    const uint16_t* __restrict__ A, const uint16_t* __restrict__ Bt,
    float* __restrict__ out, const float* __restrict__ bias) {
  const int m0 = blockIdx.y * 128, n0 = blockIdx.x * 128;
  f32x4 acc[4][4] = {};
  gemm_core(A, Bt, m0, n0, acc);

  const int tid = threadIdx.x, lane = tid & 63;
  const int l16 = lane & 15, quad = lane >> 4, w = tid >> 6;
  const int wm = (w & 1) * 64, wn = (w >> 1) * 64;
  float bv[4];
#pragma unroll
  for (int j = 0; j < 4; ++j) bv[j] = bias[n0 + wn + j * 16 + l16];
#pragma unroll
  for (int i = 0; i < 4; ++i)
#pragma unroll
    for (int j = 0; j < 4; ++j) {
      int col = n0 + wn + j * 16 + l16;
#pragma unroll
      for (int r = 0; r < 4; ++r) {
        int row = m0 + wm + i * 16 + quad * 4 + r;
        out[(size_t)row * 768 + col] = acc[i][j][r] + bv[j];
      }
    }
}

// ---------------------------------------------------------------------------
// Flash attention, NO-MAX softmax. Grid (8, 64): x = q-tile (128 rows),
// y = b*8+h. 256 threads = 4 waves; wave w owns TWO 16-row q-strips:
// rows [w*16, w*16+16) and [64+w*16, 64+w*16+16). Each K/V B-frag LDS read
// feeds 2 MFMAs (one per strip) -> half the LDS-read traffic per block.
// Double-buffered K/V staging one tile ahead; rel prefetched one tile ahead.
// p = exp2(score*log2e) directly (bounded inputs); l lane-local, DPP-reduced
// once in the epilogue.
__global__ __launch_bounds__(256, 2) void attn_kernel(
    const uint16_t* __restrict__ Q,   // [B][N][C] bf16 (pre-scaled by QSC)
    const uint16_t* __restrict__ Kb,  // [B][N][C] bf16
    const uint16_t* __restrict__ Vt,  // [B*H][HD][N] bf16
    const float* __restrict__ rel,    // [H][N][N] f32
    uint16_t* __restrict__ AO) {      // [B][N][C] bf16
  __shared__ uint16_t Ks[2][64 * 96];   // 2 x 12 KB, mixed-XOR swizzle
  __shared__ uint16_t Vs[2][96 * 64];   // 2 x 12 KB, XOR swizzle
  __shared__ uint16_t Ps[128 * 64];     // 16 KB, XOR-swizzled chunks

  const int tid = threadIdx.x;
  const int q0 = blockIdx.x * 128;
  const int bh = blockIdx.y;
  const int b = bh >> 3, h = bh & 7;
  const int w = tid >> 6, lane = tid & 63;
  const int l16 = lane & 15, quad = lane >> 4;
  const int l7 = l16 & 7;

  // Q fragments in registers, 2 strips: A-frag lane l16 -> q-row base+l16
  bf16x8 qf[2][3];
#pragma unroll
  for (int st = 0; st < 2; ++st) {
    const int qrow = q0 + st * 64 + w * 16 + l16;
    const uint16_t* qp =
        Q + ((size_t)(b * 1024 + qrow)) * 768 + h * 96 + quad * 8;
#pragma unroll
    for (int j = 0; j < 3; ++j) qf[st][j] = *(const bf16x8*)(qp + j * 32);
  }

  // staging: 768 K chunks + 768 V chunks over 256 threads = 3+3 each
  auto kSrc = [](int c) {
    int r = c / 12, pc = c % 12;
    int kc = (pc < 8) ? (pc ^ (r & 7)) : (8 + ((pc & 3) ^ (r & 3)));
    return r * 768 + kc * 8;
  };
  auto vSrc = [](int c) {
    int d = c >> 3, pc = c & 7;
    return d * 1024 + (pc ^ (d & 7)) * 8;
  };
  int koffs[3], voffs[3];
#pragma unroll
  for (int i = 0; i < 3; ++i) {
    koffs[i] = kSrc(tid + 256 * i);
    voffs[i] = vSrc(tid + 256 * i);
  }

  const uint16_t* kslab = Kb + ((size_t)(b * 1024)) * 768 + h * 96;
  const uint16_t* vslab = Vt + ((size_t)(bh * 96) << 10);
  const float* relbase0 =
      rel + ((size_t)h << 20) + ((size_t)(q0 + w * 16 + quad * 4) << 10) + l16;
  const float* relbase1 = relbase0 + (64 << 10);

  auto stage = [&](int knext, int bufi) {
    const uint16_t* kb = kslab + (size_t)knext * 768;
    const uint16_t* vb = vslab + knext;
    uint16_t* Kbuf = &Ks[bufi][0];
    uint16_t* Vbuf = &Vs[bufi][0];
#pragma unroll
    for (int i = 0; i < 3; ++i) {
      gl_lds16(kb + koffs[i], Kbuf + (tid + 256 * i) * 8);
      gl_lds16(vb + voffs[i], Vbuf + (tid + 256 * i) * 8);
    }
  };

  float relv[2][2][16];  // [buf][strip][val]
  auto loadrel = [&](int knext, float (&dst)[2][16]) {
#pragma unroll
    for (int r = 0; r < 4; ++r)
#pragma unroll
      for (int nt = 0; nt < 4; ++nt) {
        dst[0][nt * 4 + r] = relbase0[(size_t)r * 1024 + knext + nt * 16];
        dst[1][nt * 4 + r] = relbase1[(size_t)r * 1024 + knext + nt * 16];
      }
  };

  float l_i[2][4] = {};
  f32x4 o_acc[2][6] = {};

  stage(0, 0);
  loadrel(0, relv[0]);

#pragma unroll 2
  for (int kt = 0; kt < 16; ++kt) {
    const int cur = kt & 1, nxt = (kt + 1) & 1;
    __syncthreads();  // staging of cur drained; prior reads of nxt done
    if (kt < 15) {
      stage((kt + 1) * 64, nxt);
      loadrel((kt + 1) * 64, relv[nxt]);
    }
    const uint16_t* KsC = &Ks[cur][0];
    const uint16_t* VsC = &Vs[cur][0];

    // S strips (2 x 16q x 64k): each K B-frag read feeds both strips
    f32x4 s[2][4] = {};
#pragma unroll
    for (int ksi = 0; ksi < 3; ++ksi) {
#pragma unroll
      for (int nt = 0; nt < 4; ++nt) {
        const int row = nt * 16 + l16;
        const int c = ksi * 4 + quad;
        const int phys =
            (ksi < 2) ? (c ^ (row & 7)) : (8 + ((c & 3) ^ (row & 3)));
        bf16x8 kf = *(const bf16x8*)&KsC[row * 96 + phys * 8];
        s[0][nt] = mfma16(qf[0][ksi], kf, s[0][nt]);
        s[1][nt] = mfma16(qf[1][ksi], kf, s[1][nt]);
      }
    }

    // softmax (no max) + P scatter per strip
    const int khi = l16 >> 3;
#pragma unroll
    for (int st = 0; st < 2; ++st) {
      float pv[16];
#pragma unroll
      for (int nt = 0; nt < 4; ++nt)
#pragma unroll
        for (int r = 0; r < 4; ++r)
          pv[nt * 4 + r] = __builtin_amdgcn_exp2f(
              fmaf(relv[cur][st][nt * 4 + r], LOG2E, s[st][nt][r]));
#pragma unroll
      for (int r = 0; r < 4; ++r)
        l_i[st][r] += (pv[r] + pv[4 + r]) + (pv[8 + r] + pv[12 + r]);
#pragma unroll
      for (int r = 0; r < 4; ++r) {
        const int qloc = quad * 4 + r;
        const int rowoff = (st * 64 + w * 16 + qloc) * 64;
        const int sw = qloc & 7;
#pragma unroll
        for (int nt = 0; nt < 4; ++nt) {
          const int kc = 2 * nt + khi;
          Ps[rowoff + (((kc ^ sw) << 3) | l7)] = f2bf(pv[nt * 4 + r]);
        }
      }
    }
    asm volatile("s_waitcnt lgkmcnt(0)" ::: "memory");  // wave-internal W->R

    // O strips (2 x 16q x 96d): each V B-frag read feeds both strips
#pragma unroll
    for (int ksi = 0; ksi < 2; ++ksi) {
      const int phys = (ksi * 4 + quad) ^ l7;
      bf16x8 pf0 = *(const bf16x8*)&Ps[(w * 16 + l16) * 64 + phys * 8];
      bf16x8 pf1 = *(const bf16x8*)&Ps[(64 + w * 16 + l16) * 64 + phys * 8];
#pragma unroll
      for (int jt = 0; jt < 6; ++jt) {
        const int d = jt * 16 + l16;
        bf16x8 vf = *(const bf16x8*)&VsC[d * 64 + phys * 8];  // d&7 == l7
        o_acc[0][jt] = mfma16(pf0, vf, o_acc[0][jt]);
        o_acc[1][jt] = mfma16(pf1, vf, o_acc[1][jt]);
      }
    }
  }

  // epilogue: one DPP reduction per row, normalize, store bf16
#pragma unroll
  for (int st = 0; st < 2; ++st)
#pragma unroll
    for (int r = 0; r < 4; ++r) {
      float inv = 1.f / red16_add(l_i[st][r]);
      int row = q0 + st * 64 + w * 16 + quad * 4 + r;
#pragma unroll
      for (int jt = 0; jt < 6; ++jt) {
        int col = h * 96 + jt * 16 + l16;
        AO[(size_t)(b * 1024 + row) * 768 + col] = f2bf(o_acc[st][jt][r] * inv);
      }
    }
}

// ---------------------------------------------------------------------------
extern "C" void kernel_launch(void* const* d_in, const int* in_sizes, int n_in,
                              void* d_out, int out_size, void* d_ws,
                              size_t ws_size, hipStream_t stream) {
  const float* x   = (const float*)d_in[0];
  const float* y   = (const float*)d_in[1];
  const float* rel = (const float*)d_in[2];
  const float* Wq  = (const float*)d_in[5];
  const float* Wk  = (const float*)d_in[6];
  const float* Wv  = (const float*)d_in[7];
  const float* Wp  = (const float*)d_in[8];
  const float* bp  = (const float*)d_in[9];
  float* out = (float*)d_out;

  const size_t nBNC = (size_t)Bb * Nn * Cc;  // 6291456
  const size_t nW = (size_t)Cc * Cc;         // 589824

  char* ws = (char*)d_ws;
  size_t off = 0;
  auto alloc = [&](size_t bytes) {
    char* p = ws + off;
    off += (bytes + 255) & ~(size_t)255;
    return p;
  };
  uint16_t* xb  = (uint16_t*)alloc(nBNC * 2);
  uint16_t* yb  = (uint16_t*)alloc(nBNC * 2);
  uint16_t* wqb = (uint16_t*)alloc(nW * 2);
  uint16_t* wkb = (uint16_t*)alloc(nW * 2);
  uint16_t* wvb = (uint16_t*)alloc(nW * 2);
  uint16_t* wpb = (uint16_t*)alloc(nW * 2);
  uint16_t* Qb  = (uint16_t*)alloc(nBNC * 2);
  uint16_t* Kb  = (uint16_t*)alloc(nBNC * 2);
  uint16_t* Vtb = (uint16_t*)alloc(nBNC * 2);
  uint16_t* AOb = (uint16_t*)alloc(nBNC * 2);

  // 1. conversions (2 launches)
  cvt2_kernel<<<dim3((int)(nBNC / 4 / 256), 2), 256, 0, stream>>>(
      x, y, xb, yb, (int)(nBNC / 4));
  cvtw_kernel<<<dim3((int)(nW / 4 / 256), 4), 256, 0, stream>>>(
      Wq, Wk, Wv, Wp, wqb, wkb, wvb, wpb, (int)(nW / 4));

  // 2. fused QKV projections
  qkv_kernel<<<dim3(18, 64), 256, 0, stream>>>(xb, yb, wqb, wkb, wvb, Qb, Kb,
                                               Vtb);

  // 3. attention
  attn_kernel<<<dim3(8, 64), 256, 0, stream>>>(Qb, Kb, Vtb, rel, AOb);

  // 4. output projection + bias
  proj_kernel<<<dim3(6, 64), 256, 0, stream>>>(AOb, wpb, out, bp);
}

// Round 7
// 256.820 us; speedup vs baseline: 1.3683x; 1.3683x over previous
//
#include <hip/hip_runtime.h>
#include <hip/hip_bf16.h>
#include <cstdint>
#include <cstddef>

// ---------------------------------------------------------------------------
// Cross attention, B=8 N=1024 C=768 HEADS=8 HD=96, sr_ratio=1 path.
//   1. cvt: x,y -> bf16; Wq*SCALE*log2e, Wk, Wv, Wp -> bf16
//   2. fused QKV GEMM (bf16 MFMA 16x16x32, BK=64, XOR swizzle, single-barrier
//      double-buffered staging).  Q,K -> [B][N][C]; V -> [B*H][HD][N]
//   3. flash attention, NO-MAX softmax (bounded scores), 128-q tile,
//      4 waves x 2 strips of 16 q-rows (each LDS B-frag feeds 2 MFMAs),
//      double-buffered K/V staging; rel loaded per-tile into a SINGLE
//      register buffer (R6's double-buffer spilled: VGPR 128 + 70MB scratch).
//   4. proj GEMM out = AO@Wp^T + bp -> f32
// ---------------------------------------------------------------------------

using f32x4  = __attribute__((ext_vector_type(4))) float;
using bf16x8 = __attribute__((ext_vector_type(8))) __bf16;

constexpr int Bb = 8, Nn = 1024, Cc = 768;
constexpr float LOG2E = 1.4426950408889634f;
constexpr float QSC   = 0.10206207261596575f * 1.4426950408889634f;  // SCALE*log2e

__device__ __forceinline__ uint16_t f2bf(float f) {
  union { float f; uint32_t u; } v; v.f = f;
  return (uint16_t)((v.u + 0x7fffu + ((v.u >> 16) & 1u)) >> 16);  // RNE
}

__device__ __forceinline__ void gl_lds16(const void* g, void* l) {
  __builtin_amdgcn_global_load_lds(
      (const __attribute__((address_space(1))) void*)g,
      (__attribute__((address_space(3))) void*)l, 16, 0, 0);
}

__device__ __forceinline__ f32x4 mfma16(bf16x8 a, bf16x8 b, f32x4 c) {
  return __builtin_amdgcn_mfma_f32_16x16x32_bf16(a, b, c, 0, 0, 0);
}

// DPP row_ror sum over a 16-lane row (epilogue only)
template <int CTRL>
__device__ __forceinline__ float dpp_add(float v) {
  union { float f; int i; } u, r;
  u.f = v;
  r.i = __builtin_amdgcn_update_dpp(u.i, u.i, CTRL, 0xF, 0xF, false);
  return v + r.f;
}
__device__ __forceinline__ float red16_add(float v) {
  v = dpp_add<0x128>(v);  // row_ror:8
  v = dpp_add<0x124>(v);  // row_ror:4
  v = dpp_add<0x122>(v);  // row_ror:2
  v = dpp_add<0x121>(v);  // row_ror:1
  return v;
}

// ---------------------------------------------------------------------------
__global__ void cvt2_kernel(const float* __restrict__ a,
                            const float* __restrict__ b,
                            uint16_t* __restrict__ da,
                            uint16_t* __restrict__ db, int n4) {
  int i = blockIdx.x * blockDim.x + threadIdx.x;
  const float* s = blockIdx.y ? b : a;
  uint16_t* d = blockIdx.y ? db : da;
  if (i < n4) {
    float4 v = ((const float4*)s)[i];
    ushort4 o;
    o.x = f2bf(v.x); o.y = f2bf(v.y); o.z = f2bf(v.z); o.w = f2bf(v.w);
    ((ushort4*)d)[i] = o;
  }
}

__global__ void cvtw_kernel(const float* __restrict__ wq,
                            const float* __restrict__ wk,
                            const float* __restrict__ wv,
                            const float* __restrict__ wp,
                            uint16_t* __restrict__ dq, uint16_t* __restrict__ dk,
                            uint16_t* __restrict__ dv, uint16_t* __restrict__ dp,
                            int n4) {
  int i = blockIdx.x * blockDim.x + threadIdx.x;
  const float* s; uint16_t* d; float sc = 1.f;
  switch (blockIdx.y) {
    case 0:  s = wq; d = dq; sc = QSC; break;  // fold SCALE*log2e into Wq
    case 1:  s = wk; d = dk; break;
    case 2:  s = wv; d = dv; break;
    default: s = wp; d = dp; break;
  }
  if (i < n4) {
    float4 v = ((const float4*)s)[i];
    ushort4 o;
    o.x = f2bf(v.x * sc); o.y = f2bf(v.y * sc);
    o.z = f2bf(v.z * sc); o.w = f2bf(v.w * sc);
    ((ushort4*)d)[i] = o;
  }
}

// ---------------------------------------------------------------------------
// GEMM core: 128x128 tile, BK=64, XOR-swizzled LDS, single-barrier
// double-buffered staging. M=8192 N=768 K=768, A row-major, Bt = B^T.
__device__ __forceinline__ void gemm_core(const uint16_t* __restrict__ A,
                                          const uint16_t* __restrict__ Bt,
                                          int m0, int n0, f32x4 (&acc)[4][4]) {
  __shared__ uint16_t As[2][128 * 64];
  __shared__ uint16_t Bs[2][128 * 64];
  const int tid = threadIdx.x;
  const int lane = tid & 63, l16 = lane & 15, quad = lane >> 4;
  const int w = tid >> 6;
  const int wm = (w & 1) * 64, wn = (w >> 1) * 64;

  int soff[4];
#pragma unroll
  for (int i = 0; i < 4; ++i) {
    int idx = tid + 256 * i;
    int row = idx >> 3, pc = idx & 7;
    int c = pc ^ (row & 7);           // logical chunk staged at phys pc
    soff[i] = row * 768 + c * 8;
  }

  const uint16_t* Abase = A + (size_t)m0 * 768;
  const uint16_t* Bbase = Bt + (size_t)n0 * 768;
  auto stage = [&](int k0, int buf) {
#pragma unroll
    for (int i = 0; i < 4; ++i)
      gl_lds16(Abase + k0 + soff[i], &As[buf][(tid + 256 * i) * 8]);
#pragma unroll
    for (int i = 0; i < 4; ++i)
      gl_lds16(Bbase + k0 + soff[i], &Bs[buf][(tid + 256 * i) * 8]);
  };

  stage(0, 0);

#pragma unroll 2
  for (int kt = 0; kt < 12; ++kt) {
    const int cur = kt & 1, nxt = (kt + 1) & 1;
    __syncthreads();  // staging of cur drained; prior reads of nxt done
    if (kt < 11) stage((kt + 1) * 64, nxt);

#pragma unroll
    for (int ks = 0; ks < 2; ++ks) {
      bf16x8 a[4], b[4];
      const int phys = (ks * 4 + quad) ^ (l16 & 7);
#pragma unroll
      for (int i = 0; i < 4; ++i)
        a[i] = *(const bf16x8*)&As[cur][(wm + i * 16 + l16) * 64 + phys * 8];
#pragma unroll
      for (int j = 0; j < 4; ++j)
        b[j] = *(const bf16x8*)&Bs[cur][(wn + j * 16 + l16) * 64 + phys * 8];
#pragma unroll
      for (int i = 0; i < 4; ++i)
#pragma unroll
        for (int j = 0; j < 4; ++j)
          acc[i][j] = mfma16(a[i], b[j], acc[i][j]);
    }
  }
}

// Fused Q/K/V projections. Grid (18,64): x/6 -> segment {Q,K,V}.
__global__ __launch_bounds__(256, 2) void qkv_kernel(
    const uint16_t* __restrict__ xb, const uint16_t* __restrict__ yb,
    const uint16_t* __restrict__ wq, const uint16_t* __restrict__ wk,
    const uint16_t* __restrict__ wv, uint16_t* __restrict__ Qb,
    uint16_t* __restrict__ Kb, uint16_t* __restrict__ Vt) {
  const int seg = blockIdx.x / 6, nb = blockIdx.x % 6;
  const uint16_t* A  = (seg == 0) ? xb : yb;
  const uint16_t* Bt = (seg == 0) ? wq : (seg == 1) ? wk : wv;
  const int m0 = blockIdx.y * 128, n0 = nb * 128;

  f32x4 acc[4][4] = {};
  gemm_core(A, Bt, m0, n0, acc);

  const int tid = threadIdx.x, lane = tid & 63;
  const int l16 = lane & 15, quad = lane >> 4, w = tid >> 6;
  const int wm = (w & 1) * 64, wn = (w >> 1) * 64;

  if (seg <= 1) {
    uint16_t* O = seg ? Kb : Qb;
#pragma unroll
    for (int i = 0; i < 4; ++i)
#pragma unroll
      for (int j = 0; j < 4; ++j) {
        int col = n0 + wn + j * 16 + l16;
#pragma unroll
        for (int r = 0; r < 4; ++r) {
          int row = m0 + wm + i * 16 + quad * 4 + r;
          O[(size_t)row * 768 + col] = f2bf(acc[i][j][r]);
        }
      }
  } else {
    // V scatter: Vt[b*8+h][hd][n]
#pragma unroll
    for (int i = 0; i < 4; ++i) {
      int row0 = m0 + wm + i * 16 + quad * 4;
      int bidx = row0 >> 10, nseq = row0 & 1023;
#pragma unroll
      for (int j = 0; j < 4; ++j) {
        int col = n0 + wn + j * 16 + l16;
        int h = col / 96, hd = col % 96;
        ushort4 pk;
        pk.x = f2bf(acc[i][j][0]); pk.y = f2bf(acc[i][j][1]);
        pk.z = f2bf(acc[i][j][2]); pk.w = f2bf(acc[i][j][3]);
        size_t o = (((size_t)(bidx * 8 + h) * 96 + hd) << 10) + nseq;
        *(ushort4*)(Vt + o) = pk;
      }
    }
  }
}

// Output projection: out = AO@Wp^T + bp (f32). Grid (6,64).
__global__ __launch_bounds__(256, 2) void proj_kernel(
    const uint16_t* __restrict__ A, const uint16_t* __restrict__ Bt,
    float* __restrict__ out, const float* __restrict__ bias) {
  const int m0 = blockIdx.y * 128, n0 = blockIdx.x * 128;
  f32x4 acc[4][4] = {};
  gemm_core(A, Bt, m0, n0, acc);

  const int tid = threadIdx.x, lane = tid & 63;
  const int l16 = lane & 15, quad = lane >> 4, w = tid >> 6;
  const int wm = (w & 1) * 64, wn = (w >> 1) * 64;
  float bv[4];
#pragma unroll
  for (int j = 0; j < 4; ++j) bv[j] = bias[n0 + wn + j * 16 + l16];
#pragma unroll
  for (int i = 0; i < 4; ++i)
#pragma unroll
    for (int j = 0; j < 4; ++j) {
      int col = n0 + wn + j * 16 + l16;
#pragma unroll
      for (int r = 0; r < 4; ++r) {
        int row = m0 + wm + i * 16 + quad * 4 + r;
        out[(size_t)row * 768 + col] = acc[i][j][r] + bv[j];
      }
    }
}

// ---------------------------------------------------------------------------
// Flash attention, NO-MAX softmax. Grid (8, 64): x = q-tile (128 rows),
// y = b*8+h. 256 threads = 4 waves; wave w owns TWO 16-row q-strips:
// rows [w*16, w*16+16) and [64+w*16, 64+w*16+16). Each K/V B-frag LDS read
// feeds 2 MFMAs (one per strip) -> half the LDS-read traffic per MFMA.
// Double-buffered K/V staging one tile ahead. rel bias: SINGLE register
// buffer relv[2][16] (per strip), prefetched for tile kt+1 after the
// softmax of tile kt has consumed it (hides behind PV + barrier; vmcnt
// drains at the pre-barrier wait). l lane-local, DPP-reduced in epilogue.
__global__ __launch_bounds__(256, 2) void attn_kernel(
    const uint16_t* __restrict__ Q,   // [B][N][C] bf16 (pre-scaled by QSC)
    const uint16_t* __restrict__ Kb,  // [B][N][C] bf16
    const uint16_t* __restrict__ Vt,  // [B*H][HD][N] bf16
    const float* __restrict__ rel,    // [H][N][N] f32
    uint16_t* __restrict__ AO) {      // [B][N][C] bf16
  __shared__ uint16_t Ks[2][64 * 96];   // 2 x 12 KB, mixed-XOR swizzle
  __shared__ uint16_t Vs[2][96 * 64];   // 2 x 12 KB, XOR swizzle
  __shared__ uint16_t Ps[128 * 64];     // 16 KB, XOR-swizzled chunks

  const int tid = threadIdx.x;
  const int q0 = blockIdx.x * 128;
  const int bh = blockIdx.y;
  const int b = bh >> 3, h = bh & 7;
  const int w = tid >> 6, lane = tid & 63;
  const int l16 = lane & 15, quad = lane >> 4;
  const int l7 = l16 & 7;

  // Q fragments in registers, 2 strips: A-frag lane l16 -> q-row base+l16
  bf16x8 qf[2][3];
#pragma unroll
  for (int st = 0; st < 2; ++st) {
    const int qrow = q0 + st * 64 + w * 16 + l16;
    const uint16_t* qp =
        Q + ((size_t)(b * 1024 + qrow)) * 768 + h * 96 + quad * 8;
#pragma unroll
    for (int j = 0; j < 3; ++j) qf[st][j] = *(const bf16x8*)(qp + j * 32);
  }

  // staging: 768 K chunks + 768 V chunks over 256 threads = 3+3 each
  auto kSrc = [](int c) {
    int r = c / 12, pc = c % 12;
    int kc = (pc < 8) ? (pc ^ (r & 7)) : (8 + ((pc & 3) ^ (r & 3)));
    return r * 768 + kc * 8;
  };
  auto vSrc = [](int c) {
    int d = c >> 3, pc = c & 7;
    return d * 1024 + (pc ^ (d & 7)) * 8;
  };
  int koffs[3], voffs[3];
#pragma unroll
  for (int i = 0; i < 3; ++i) {
    koffs[i] = kSrc(tid + 256 * i);
    voffs[i] = vSrc(tid + 256 * i);
  }

  const uint16_t* kslab = Kb + ((size_t)(b * 1024)) * 768 + h * 96;
  const uint16_t* vslab = Vt + ((size_t)(bh * 96) << 10);
  const float* relbase0 =
      rel + ((size_t)h << 20) + ((size_t)(q0 + w * 16 + quad * 4) << 10) + l16;
  const float* relbase1 = relbase0 + (64 << 10);

  auto stage = [&](int knext, int bufi) {
    const uint16_t* kb = kslab + (size_t)knext * 768;
    const uint16_t* vb = vslab + knext;
    uint16_t* Kbuf = &Ks[bufi][0];
    uint16_t* Vbuf = &Vs[bufi][0];
#pragma unroll
    for (int i = 0; i < 3; ++i) {
      gl_lds16(kb + koffs[i], Kbuf + (tid + 256 * i) * 8);
      gl_lds16(vb + voffs[i], Vbuf + (tid + 256 * i) * 8);
    }
  };

  float relv[2][16];  // [strip][val] -- single buffer (R6 dbuf spilled)
  auto loadrel = [&](int knext) {
#pragma unroll
    for (int r = 0; r < 4; ++r)
#pragma unroll
      for (int nt = 0; nt < 4; ++nt) {
        relv[0][nt * 4 + r] = relbase0[(size_t)r * 1024 + knext + nt * 16];
        relv[1][nt * 4 + r] = relbase1[(size_t)r * 1024 + knext + nt * 16];
      }
  };

  float l_i[2][4] = {};
  f32x4 o_acc[2][6] = {};

  stage(0, 0);
  loadrel(0);

#pragma unroll 2
  for (int kt = 0; kt < 16; ++kt) {
    const int cur = kt & 1, nxt = (kt + 1) & 1;
    __syncthreads();  // staging of cur drained; prior reads of nxt done
    if (kt < 15) stage((kt + 1) * 64, nxt);
    const uint16_t* KsC = &Ks[cur][0];
    const uint16_t* VsC = &Vs[cur][0];

    // S strips (2 x 16q x 64k): each K B-frag read feeds both strips
    f32x4 s[2][4] = {};
#pragma unroll
    for (int ksi = 0; ksi < 3; ++ksi) {
#pragma unroll
      for (int nt = 0; nt < 4; ++nt) {
        const int row = nt * 16 + l16;
        const int c = ksi * 4 + quad;
        const int phys =
            (ksi < 2) ? (c ^ (row & 7)) : (8 + ((c & 3) ^ (row & 3)));
        bf16x8 kf = *(const bf16x8*)&KsC[row * 96 + phys * 8];
        s[0][nt] = mfma16(qf[0][ksi], kf, s[0][nt]);
        s[1][nt] = mfma16(qf[1][ksi], kf, s[1][nt]);
      }
    }

    // softmax (no max) + P scatter per strip; consumes relv[st]
    const int khi = l16 >> 3;
#pragma unroll
    for (int st = 0; st < 2; ++st) {
      float pv[16];
#pragma unroll
      for (int nt = 0; nt < 4; ++nt)
#pragma unroll
        for (int r = 0; r < 4; ++r)
          pv[nt * 4 + r] = __builtin_amdgcn_exp2f(
              fmaf(relv[st][nt * 4 + r], LOG2E, s[st][nt][r]));
#pragma unroll
      for (int r = 0; r < 4; ++r)
        l_i[st][r] += (pv[r] + pv[4 + r]) + (pv[8 + r] + pv[12 + r]);
#pragma unroll
      for (int r = 0; r < 4; ++r) {
        const int qloc = quad * 4 + r;
        const int rowoff = (st * 64 + w * 16 + qloc) * 64;
        const int sw = qloc & 7;
#pragma unroll
        for (int nt = 0; nt < 4; ++nt) {
          const int kc = 2 * nt + khi;
          Ps[rowoff + (((kc ^ sw) << 3) | l7)] = f2bf(pv[nt * 4 + r]);
        }
      }
    }

    // relv now dead: prefetch next tile's bias (hides behind PV + barrier)
    if (kt < 15) loadrel((kt + 1) * 64);

    asm volatile("s_waitcnt lgkmcnt(0)" ::: "memory");  // wave-internal W->R

    // O strips (2 x 16q x 96d): each V B-frag read feeds both strips
#pragma unroll
    for (int ksi = 0; ksi < 2; ++ksi) {
      const int phys = (ksi * 4 + quad) ^ l7;
      bf16x8 pf0 = *(const bf16x8*)&Ps[(w * 16 + l16) * 64 + phys * 8];
      bf16x8 pf1 = *(const bf16x8*)&Ps[(64 + w * 16 + l16) * 64 + phys * 8];
#pragma unroll
      for (int jt = 0; jt < 6; ++jt) {
        const int d = jt * 16 + l16;
        bf16x8 vf = *(const bf16x8*)&VsC[d * 64 + phys * 8];  // d&7 == l7
        o_acc[0][jt] = mfma16(pf0, vf, o_acc[0][jt]);
        o_acc[1][jt] = mfma16(pf1, vf, o_acc[1][jt]);
      }
    }
  }

  // epilogue: one DPP reduction per row, normalize, store bf16
#pragma unroll
  for (int st = 0; st < 2; ++st)
#pragma unroll
    for (int r = 0; r < 4; ++r) {
      float inv = 1.f / red16_add(l_i[st][r]);
      int row = q0 + st * 64 + w * 16 + quad * 4 + r;
#pragma unroll
      for (int jt = 0; jt < 6; ++jt) {
        int col = h * 96 + jt * 16 + l16;
        AO[(size_t)(b * 1024 + row) * 768 + col] = f2bf(o_acc[st][jt][r] * inv);
      }
    }
}

// ---------------------------------------------------------------------------
extern "C" void kernel_launch(void* const* d_in, const int* in_sizes, int n_in,
                              void* d_out, int out_size, void* d_ws,
                              size_t ws_size, hipStream_t stream) {
  const float* x   = (const float*)d_in[0];
  const float* y   = (const float*)d_in[1];
  const float* rel = (const float*)d_in[2];
  const float* Wq  = (const float*)d_in[5];
  const float* Wk  = (const float*)d_in[6];
  const float* Wv  = (const float*)d_in[7];
  const float* Wp  = (const float*)d_in[8];
  const float* bp  = (const float*)d_in[9];
  float* out = (float*)d_out;

  const size_t nBNC = (size_t)Bb * Nn * Cc;  // 6291456
  const size_t nW = (size_t)Cc * Cc;         // 589824

  char* ws = (char*)d_ws;
  size_t off = 0;
  auto alloc = [&](size_t bytes) {
    char* p = ws + off;
    off += (bytes + 255) & ~(size_t)255;
    return p;
  };
  uint16_t* xb  = (uint16_t*)alloc(nBNC * 2);
  uint16_t* yb  = (uint16_t*)alloc(nBNC * 2);
  uint16_t* wqb = (uint16_t*)alloc(nW * 2);
  uint16_t* wkb = (uint16_t*)alloc(nW * 2);
  uint16_t* wvb = (uint16_t*)alloc(nW * 2);
  uint16_t* wpb = (uint16_t*)alloc(nW * 2);
  uint16_t* Qb  = (uint16_t*)alloc(nBNC * 2);
  uint16_t* Kb  = (uint16_t*)alloc(nBNC * 2);
  uint16_t* Vtb = (uint16_t*)alloc(nBNC * 2);
  uint16_t* AOb = (uint16_t*)alloc(nBNC * 2);

  // 1. conversions (2 launches)
  cvt2_kernel<<<dim3((int)(nBNC / 4 / 256), 2), 256, 0, stream>>>(
      x, y, xb, yb, (int)(nBNC / 4));
  cvtw_kernel<<<dim3((int)(nW / 4 / 256), 4), 256, 0, stream>>>(
      Wq, Wk, Wv, Wp, wqb, wkb, wvb, wpb, (int)(nW / 4));

  // 2. fused QKV projections
  qkv_kernel<<<dim3(18, 64), 256, 0, stream>>>(xb, yb, wqb, wkb, wvb, Qb, Kb,
                                               Vtb);

  // 3. attention
  attn_kernel<<<dim3(8, 64), 256, 0, stream>>>(Qb, Kb, Vtb, rel, AOb);

  // 4. output projection + bias
  proj_kernel<<<dim3(6, 64), 256, 0, stream>>>(AOb, wpb, out, bp);
}

// Round 8
// 238.433 us; speedup vs baseline: 1.4739x; 1.0771x over previous
//
#include <hip/hip_runtime.h>
#include <hip/hip_bf16.h>
#include <cstdint>
#include <cstddef>

// ---------------------------------------------------------------------------
// Cross attention, B=8 N=1024 C=768 HEADS=8 HD=96, sr_ratio=1 path.
//   1. cvt_all: single launch; x,y -> bf16; Wq*QSC, Wk, Wv, Wp -> bf16
//   2. fused QKV GEMM (bf16 MFMA 16x16x32, BK=64, XOR swizzle, 2-barrier)
//      Q,K -> [B][N][C]; V -> [B*H][HD][N] via LDS transpose + coalesced b128
//   3. flash attention (R7 structure, 60us): NO-MAX softmax, 128-q tile,
//      4 waves x 2 strips, double-buffered K/V staging, reg-resident Q.
//   4. proj GEMM 64x128 tiles (grid 768 -> no tail), out = AO@Wp^T + bp
// ---------------------------------------------------------------------------

using f32x4  = __attribute__((ext_vector_type(4))) float;
using bf16x8 = __attribute__((ext_vector_type(8))) __bf16;

constexpr int Bb = 8, Nn = 1024, Cc = 768;
constexpr float LOG2E = 1.4426950408889634f;
constexpr float QSC   = 0.10206207261596575f * 1.4426950408889634f;  // SCALE*log2e

__device__ __forceinline__ uint16_t f2bf(float f) {
  union { float f; uint32_t u; } v; v.f = f;
  return (uint16_t)((v.u + 0x7fffu + ((v.u >> 16) & 1u)) >> 16);  // RNE
}

__device__ __forceinline__ void gl_lds16(const void* g, void* l) {
  __builtin_amdgcn_global_load_lds(
      (const __attribute__((address_space(1))) void*)g,
      (__attribute__((address_space(3))) void*)l, 16, 0, 0);
}

__device__ __forceinline__ f32x4 mfma16(bf16x8 a, bf16x8 b, f32x4 c) {
  return __builtin_amdgcn_mfma_f32_16x16x32_bf16(a, b, c, 0, 0, 0);
}

// DPP row_ror sum over a 16-lane row (epilogue only)
template <int CTRL>
__device__ __forceinline__ float dpp_add(float v) {
  union { float f; int i; } u, r;
  u.f = v;
  r.i = __builtin_amdgcn_update_dpp(u.i, u.i, CTRL, 0xF, 0xF, false);
  return v + r.f;
}
__device__ __forceinline__ float red16_add(float v) {
  v = dpp_add<0x128>(v);  // row_ror:8
  v = dpp_add<0x124>(v);  // row_ror:4
  v = dpp_add<0x122>(v);  // row_ror:2
  v = dpp_add<0x121>(v);  // row_ror:1
  return v;
}

// ---------------------------------------------------------------------------
// Single conversion launch for all six tensors (flat-indexed in float4s).
constexpr int NX4 = (Bb * Nn * Cc) / 4;  // 1572864
constexpr int NW4 = (Cc * Cc) / 4;       // 147456
__global__ void cvt_all(const float* __restrict__ x, const float* __restrict__ y,
                        const float* __restrict__ wq, const float* __restrict__ wk,
                        const float* __restrict__ wv, const float* __restrict__ wp,
                        uint16_t* __restrict__ xb, uint16_t* __restrict__ yb,
                        uint16_t* __restrict__ dq, uint16_t* __restrict__ dk,
                        uint16_t* __restrict__ dv, uint16_t* __restrict__ dp) {
  int i = blockIdx.x * blockDim.x + threadIdx.x;
  const float* s; uint16_t* d; int off; float sc = 1.f;
  if (i < NX4) {
    s = x; d = xb; off = i;
  } else if (i < 2 * NX4) {
    s = y; d = yb; off = i - NX4;
  } else {
    int j = i - 2 * NX4;
    int wsel = j / NW4;
    off = j - wsel * NW4;
    switch (wsel) {
      case 0:  s = wq; d = dq; sc = QSC; break;
      case 1:  s = wk; d = dk; break;
      case 2:  s = wv; d = dv; break;
      default: s = wp; d = dp; break;
    }
  }
  float4 v = ((const float4*)s)[off];
  ushort4 o;
  o.x = f2bf(v.x * sc); o.y = f2bf(v.y * sc);
  o.z = f2bf(v.z * sc); o.w = f2bf(v.w * sc);
  ((ushort4*)d)[off] = o;
}

// ---------------------------------------------------------------------------
// GEMM core: 128x128 tile, BK=64, XOR-swizzled LDS, 2-barrier K-loop.
// As/Bs carved from caller smem (As = smem[0..8191], Bs = smem[8192..16383]).
__device__ __forceinline__ void gemm_core(const uint16_t* __restrict__ A,
                                          const uint16_t* __restrict__ Bt,
                                          uint16_t* As, uint16_t* Bs,
                                          int m0, int n0, f32x4 (&acc)[4][4]) {
  const int tid = threadIdx.x;
  const int lane = tid & 63, l16 = lane & 15, quad = lane >> 4;
  const int w = tid >> 6;
  const int wm = (w & 1) * 64, wn = (w >> 1) * 64;

  int soff[4];
#pragma unroll
  for (int i = 0; i < 4; ++i) {
    int idx = tid + 256 * i;
    int row = idx >> 3, pc = idx & 7;
    int c = pc ^ (row & 7);           // logical chunk staged at phys pc
    soff[i] = row * 768 + c * 8;
  }

  for (int k0 = 0; k0 < 768; k0 += 64) {
    __syncthreads();
#pragma unroll
    for (int i = 0; i < 4; ++i)
      gl_lds16(A + (size_t)m0 * 768 + k0 + soff[i], &As[(tid + 256 * i) * 8]);
#pragma unroll
    for (int i = 0; i < 4; ++i)
      gl_lds16(Bt + (size_t)n0 * 768 + k0 + soff[i], &Bs[(tid + 256 * i) * 8]);
    __syncthreads();

#pragma unroll
    for (int ks = 0; ks < 2; ++ks) {
      bf16x8 a[4], b[4];
      const int phys = (ks * 4 + quad) ^ (l16 & 7);
#pragma unroll
      for (int i = 0; i < 4; ++i)
        a[i] = *(const bf16x8*)&As[(wm + i * 16 + l16) * 64 + phys * 8];
#pragma unroll
      for (int j = 0; j < 4; ++j)
        b[j] = *(const bf16x8*)&Bs[(wn + j * 16 + l16) * 64 + phys * 8];
#pragma unroll
      for (int i = 0; i < 4; ++i)
#pragma unroll
        for (int j = 0; j < 4; ++j)
          acc[i][j] = mfma16(a[i], b[j], acc[i][j]);
    }
  }
}

// Fused Q/K/V projections. Grid (18,64): x/6 -> segment {Q,K,V}.
// V epilogue: LDS transpose (stride 130 pad) + coalesced b128 stores.
__global__ __launch_bounds__(256, 3) void qkv_kernel(
    const uint16_t* __restrict__ xb, const uint16_t* __restrict__ yb,
    const uint16_t* __restrict__ wq, const uint16_t* __restrict__ wk,
    const uint16_t* __restrict__ wv, uint16_t* __restrict__ Qb,
    uint16_t* __restrict__ Kb, uint16_t* __restrict__ Vt) {
  __shared__ uint16_t smem[128 * 130];  // 33.3 KB: staging (32 KB) / transpose
  const int seg = blockIdx.x / 6, nb = blockIdx.x % 6;
  const uint16_t* A  = (seg == 0) ? xb : yb;
  const uint16_t* Bt = (seg == 0) ? wq : (seg == 1) ? wk : wv;
  const int m0 = blockIdx.y * 128, n0 = nb * 128;

  f32x4 acc[4][4] = {};
  gemm_core(A, Bt, smem, smem + 8192, m0, n0, acc);

  const int tid = threadIdx.x, lane = tid & 63;
  const int l16 = lane & 15, quad = lane >> 4, w = tid >> 6;
  const int wm = (w & 1) * 64, wn = (w >> 1) * 64;

  if (seg <= 1) {
    uint16_t* O = seg ? Kb : Qb;
#pragma unroll
    for (int i = 0; i < 4; ++i)
#pragma unroll
      for (int j = 0; j < 4; ++j) {
        int col = n0 + wn + j * 16 + l16;
#pragma unroll
        for (int r = 0; r < 4; ++r) {
          int row = m0 + wm + i * 16 + quad * 4 + r;
          O[(size_t)row * 768 + col] = f2bf(acc[i][j][r]);
        }
      }
  } else {
    // V: transpose in LDS, then coalesced b128 stores to Vt[b8h][hd][n]
    __syncthreads();  // all staging reads done; safe to overwrite smem
#pragma unroll
    for (int i = 0; i < 4; ++i)
#pragma unroll
      for (int j = 0; j < 4; ++j) {
        int ml = wm + i * 16 + quad * 4;   // local m (4 consecutive rows)
        int nl = wn + j * 16 + l16;        // local channel
        ushort4 pk;
        pk.x = f2bf(acc[i][j][0]); pk.y = f2bf(acc[i][j][1]);
        pk.z = f2bf(acc[i][j][2]); pk.w = f2bf(acc[i][j][3]);
        *(ushort4*)&smem[nl * 130 + ml] = pk;  // T[n][m], m-contiguous
      }
    __syncthreads();
    const int bidx = m0 >> 10, nseq0 = m0 & 1023;
#pragma unroll
    for (int pass = 0; pass < 8; ++pass) {
      int nl = pass * 16 + (tid >> 4);     // local channel 0..127
      int col = n0 + nl;
      int h = col / 96, hd = col % 96;
      int m = (tid & 15) * 8;              // m-chunk base
      bf16x8 v = *(const bf16x8*)&smem[nl * 130 + m];
      size_t o = (((size_t)(bidx * 8 + h) * 96 + hd) << 10) + nseq0 + m;
      *(bf16x8*)(Vt + o) = v;              // 16 lanes x 16B contiguous
    }
  }
}

// Output projection: 64x128 tile, grid (6,128). out = AO@Wp^T + bp (f32).
__global__ __launch_bounds__(256, 4) void proj_kernel(
    const uint16_t* __restrict__ A, const uint16_t* __restrict__ Bt,
    float* __restrict__ out, const float* __restrict__ bias) {
  __shared__ uint16_t As[64 * 64];    // 8 KB
  __shared__ uint16_t Bs[128 * 64];   // 16 KB
  const int m0 = blockIdx.y * 64, n0 = blockIdx.x * 128;
  const int tid = threadIdx.x, lane = tid & 63;
  const int l16 = lane & 15, quad = lane >> 4, w = tid >> 6;
  const int wm = (w & 1) * 32, wn = (w >> 1) * 64;

  int soffA[2], soffB[4];
#pragma unroll
  for (int i = 0; i < 2; ++i) {
    int idx = tid + 256 * i;           // 512 A chunks
    int row = idx >> 3, pc = idx & 7;
    soffA[i] = row * 768 + (pc ^ (row & 7)) * 8;
  }
#pragma unroll
  for (int i = 0; i < 4; ++i) {
    int idx = tid + 256 * i;           // 1024 B chunks
    int row = idx >> 3, pc = idx & 7;
    soffB[i] = row * 768 + (pc ^ (row & 7)) * 8;
  }

  f32x4 acc[2][4] = {};
  for (int k0 = 0; k0 < 768; k0 += 64) {
    __syncthreads();
#pragma unroll
    for (int i = 0; i < 2; ++i)
      gl_lds16(A + (size_t)m0 * 768 + k0 + soffA[i], &As[(tid + 256 * i) * 8]);
#pragma unroll
    for (int i = 0; i < 4; ++i)
      gl_lds16(Bt + (size_t)n0 * 768 + k0 + soffB[i], &Bs[(tid + 256 * i) * 8]);
    __syncthreads();
#pragma unroll
    for (int ks = 0; ks < 2; ++ks) {
      bf16x8 a[2], b[4];
      const int phys = (ks * 4 + quad) ^ (l16 & 7);
#pragma unroll
      for (int i = 0; i < 2; ++i)
        a[i] = *(const bf16x8*)&As[(wm + i * 16 + l16) * 64 + phys * 8];
#pragma unroll
      for (int j = 0; j < 4; ++j)
        b[j] = *(const bf16x8*)&Bs[(wn + j * 16 + l16) * 64 + phys * 8];
#pragma unroll
      for (int i = 0; i < 2; ++i)
#pragma unroll
        for (int j = 0; j < 4; ++j)
          acc[i][j] = mfma16(a[i], b[j], acc[i][j]);
    }
  }

  float bv[4];
#pragma unroll
  for (int j = 0; j < 4; ++j) bv[j] = bias[n0 + wn + j * 16 + l16];
#pragma unroll
  for (int i = 0; i < 2; ++i)
#pragma unroll
    for (int j = 0; j < 4; ++j) {
      int col = n0 + wn + j * 16 + l16;
#pragma unroll
      for (int r = 0; r < 4; ++r) {
        int row = m0 + wm + i * 16 + quad * 4 + r;
        out[(size_t)row * 768 + col] = acc[i][j][r] + bv[j];
      }
    }
}

// ---------------------------------------------------------------------------
// Flash attention, NO-MAX softmax (R7 structure, unchanged). Grid (8, 64).
__global__ __launch_bounds__(256, 2) void attn_kernel(
    const uint16_t* __restrict__ Q,   // [B][N][C] bf16 (pre-scaled by QSC)
    const uint16_t* __restrict__ Kb,  // [B][N][C] bf16
    const uint16_t* __restrict__ Vt,  // [B*H][HD][N] bf16
    const float* __restrict__ rel,    // [H][N][N] f32
    uint16_t* __restrict__ AO) {      // [B][N][C] bf16
  __shared__ uint16_t Ks[2][64 * 96];   // 2 x 12 KB, mixed-XOR swizzle
  __shared__ uint16_t Vs[2][96 * 64];   // 2 x 12 KB, XOR swizzle
  __shared__ uint16_t Ps[128 * 64];     // 16 KB, XOR-swizzled chunks

  const int tid = threadIdx.x;
  const int q0 = blockIdx.x * 128;
  const int bh = blockIdx.y;
  const int b = bh >> 3, h = bh & 7;
  const int w = tid >> 6, lane = tid & 63;
  const int l16 = lane & 15, quad = lane >> 4;
  const int l7 = l16 & 7;

  // Q fragments in registers, 2 strips
  bf16x8 qf[2][3];
#pragma unroll
  for (int st = 0; st < 2; ++st) {
    const int qrow = q0 + st * 64 + w * 16 + l16;
    const uint16_t* qp =
        Q + ((size_t)(b * 1024 + qrow)) * 768 + h * 96 + quad * 8;
#pragma unroll
    for (int j = 0; j < 3; ++j) qf[st][j] = *(const bf16x8*)(qp + j * 32);
  }

  auto kSrc = [](int c) {
    int r = c / 12, pc = c % 12;
    int kc = (pc < 8) ? (pc ^ (r & 7)) : (8 + ((pc & 3) ^ (r & 3)));
    return r * 768 + kc * 8;
  };
  auto vSrc = [](int c) {
    int d = c >> 3, pc = c & 7;
    return d * 1024 + (pc ^ (d & 7)) * 8;
  };
  int koffs[3], voffs[3];
#pragma unroll
  for (int i = 0; i < 3; ++i) {
    koffs[i] = kSrc(tid + 256 * i);
    voffs[i] = vSrc(tid + 256 * i);
  }

  const uint16_t* kslab = Kb + ((size_t)(b * 1024)) * 768 + h * 96;
  const uint16_t* vslab = Vt + ((size_t)(bh * 96) << 10);
  const float* relbase0 =
      rel + ((size_t)h << 20) + ((size_t)(q0 + w * 16 + quad * 4) << 10) + l16;
  const float* relbase1 = relbase0 + (64 << 10);

  auto stage = [&](int knext, int bufi) {
    const uint16_t* kb = kslab + (size_t)knext * 768;
    const uint16_t* vb = vslab + knext;
    uint16_t* Kbuf = &Ks[bufi][0];
    uint16_t* Vbuf = &Vs[bufi][0];
#pragma unroll
    for (int i = 0; i < 3; ++i) {
      gl_lds16(kb + koffs[i], Kbuf + (tid + 256 * i) * 8);
      gl_lds16(vb + voffs[i], Vbuf + (tid + 256 * i) * 8);
    }
  };

  float relv[2][16];  // [strip][val] single buffer
  auto loadrel = [&](int knext) {
#pragma unroll
    for (int r = 0; r < 4; ++r)
#pragma unroll
      for (int nt = 0; nt < 4; ++nt) {
        relv[0][nt * 4 + r] = relbase0[(size_t)r * 1024 + knext + nt * 16];
        relv[1][nt * 4 + r] = relbase1[(size_t)r * 1024 + knext + nt * 16];
      }
  };

  float l_i[2][4] = {};
  f32x4 o_acc[2][6] = {};

  stage(0, 0);
  loadrel(0);

#pragma unroll 2
  for (int kt = 0; kt < 16; ++kt) {
    const int cur = kt & 1, nxt = (kt + 1) & 1;
    __syncthreads();  // staging of cur drained; prior reads of nxt done
    if (kt < 15) stage((kt + 1) * 64, nxt);
    const uint16_t* KsC = &Ks[cur][0];
    const uint16_t* VsC = &Vs[cur][0];

    // S strips (2 x 16q x 64k): each K B-frag read feeds both strips
    f32x4 s[2][4] = {};
#pragma unroll
    for (int ksi = 0; ksi < 3; ++ksi) {
#pragma unroll
      for (int nt = 0; nt < 4; ++nt) {
        const int row = nt * 16 + l16;
        const int c = ksi * 4 + quad;
        const int phys =
            (ksi < 2) ? (c ^ (row & 7)) : (8 + ((c & 3) ^ (row & 3)));
        bf16x8 kf = *(const bf16x8*)&KsC[row * 96 + phys * 8];
        s[0][nt] = mfma16(qf[0][ksi], kf, s[0][nt]);
        s[1][nt] = mfma16(qf[1][ksi], kf, s[1][nt]);
      }
    }

    // softmax (no max) + P scatter per strip; consumes relv[st]
    const int khi = l16 >> 3;
#pragma unroll
    for (int st = 0; st < 2; ++st) {
      float pv[16];
#pragma unroll
      for (int nt = 0; nt < 4; ++nt)
#pragma unroll
        for (int r = 0; r < 4; ++r)
          pv[nt * 4 + r] = __builtin_amdgcn_exp2f(
              fmaf(relv[st][nt * 4 + r], LOG2E, s[st][nt][r]));
#pragma unroll
      for (int r = 0; r < 4; ++r)
        l_i[st][r] += (pv[r] + pv[4 + r]) + (pv[8 + r] + pv[12 + r]);
#pragma unroll
      for (int r = 0; r < 4; ++r) {
        const int qloc = quad * 4 + r;
        const int rowoff = (st * 64 + w * 16 + qloc) * 64;
        const int sw = qloc & 7;
#pragma unroll
        for (int nt = 0; nt < 4; ++nt) {
          const int kc = 2 * nt + khi;
          Ps[rowoff + (((kc ^ sw) << 3) | l7)] = f2bf(pv[nt * 4 + r]);
        }
      }
    }

    // relv dead: prefetch next tile's bias (hides behind PV + barrier)
    if (kt < 15) loadrel((kt + 1) * 64);

    asm volatile("s_waitcnt lgkmcnt(0)" ::: "memory");  // wave-internal W->R

    // O strips (2 x 16q x 96d): each V B-frag read feeds both strips
#pragma unroll
    for (int ksi = 0; ksi < 2; ++ksi) {
      const int phys = (ksi * 4 + quad) ^ l7;
      bf16x8 pf0 = *(const bf16x8*)&Ps[(w * 16 + l16) * 64 + phys * 8];
      bf16x8 pf1 = *(const bf16x8*)&Ps[(64 + w * 16 + l16) * 64 + phys * 8];
#pragma unroll
      for (int jt = 0; jt < 6; ++jt) {
        const int d = jt * 16 + l16;
        bf16x8 vf = *(const bf16x8*)&VsC[d * 64 + phys * 8];  // d&7 == l7
        o_acc[0][jt] = mfma16(pf0, vf, o_acc[0][jt]);
        o_acc[1][jt] = mfma16(pf1, vf, o_acc[1][jt]);
      }
    }
  }

  // epilogue: one DPP reduction per row, normalize, store bf16
#pragma unroll
  for (int st = 0; st < 2; ++st)
#pragma unroll
    for (int r = 0; r < 4; ++r) {
      float inv = 1.f / red16_add(l_i[st][r]);
      int row = q0 + st * 64 + w * 16 + quad * 4 + r;
#pragma unroll
      for (int jt = 0; jt < 6; ++jt) {
        int col = h * 96 + jt * 16 + l16;
        AO[(size_t)(b * 1024 + row) * 768 + col] = f2bf(o_acc[st][jt][r] * inv);
      }
    }
}

// ---------------------------------------------------------------------------
extern "C" void kernel_launch(void* const* d_in, const int* in_sizes, int n_in,
                              void* d_out, int out_size, void* d_ws,
                              size_t ws_size, hipStream_t stream) {
  const float* x   = (const float*)d_in[0];
  const float* y   = (const float*)d_in[1];
  const float* rel = (const float*)d_in[2];
  const float* Wq  = (const float*)d_in[5];
  const float* Wk  = (const float*)d_in[6];
  const float* Wv  = (const float*)d_in[7];
  const float* Wp  = (const float*)d_in[8];
  const float* bp  = (const float*)d_in[9];
  float* out = (float*)d_out;

  const size_t nBNC = (size_t)Bb * Nn * Cc;  // 6291456
  const size_t nW = (size_t)Cc * Cc;         // 589824

  char* ws = (char*)d_ws;
  size_t off = 0;
  auto alloc = [&](size_t bytes) {
    char* p = ws + off;
    off += (bytes + 255) & ~(size_t)255;
    return p;
  };
  uint16_t* xb  = (uint16_t*)alloc(nBNC * 2);
  uint16_t* yb  = (uint16_t*)alloc(nBNC * 2);
  uint16_t* wqb = (uint16_t*)alloc(nW * 2);
  uint16_t* wkb = (uint16_t*)alloc(nW * 2);
  uint16_t* wvb = (uint16_t*)alloc(nW * 2);
  uint16_t* wpb = (uint16_t*)alloc(nW * 2);
  uint16_t* Qb  = (uint16_t*)alloc(nBNC * 2);
  uint16_t* Kb  = (uint16_t*)alloc(nBNC * 2);
  uint16_t* Vtb = (uint16_t*)alloc(nBNC * 2);
  uint16_t* AOb = (uint16_t*)alloc(nBNC * 2);

  // 1. all conversions, one launch (14592 blocks exactly)
  const int cvtBlocks = (2 * NX4 + 4 * NW4) / 256;
  cvt_all<<<cvtBlocks, 256, 0, stream>>>(x, y, Wq, Wk, Wv, Wp, xb, yb, wqb,
                                         wkb, wvb, wpb);

  // 2. fused QKV projections
  qkv_kernel<<<dim3(18, 64), 256, 0, stream>>>(xb, yb, wqb, wkb, wvb, Qb, Kb,
                                               Vtb);

  // 3. attention
  attn_kernel<<<dim3(8, 64), 256, 0, stream>>>(Qb, Kb, Vtb, rel, AOb);

  // 4. output projection + bias (64-row tiles, 768 blocks)
  proj_kernel<<<dim3(6, 128), 256, 0, stream>>>(AOb, wpb, out, bp);
}